// Round 5
// baseline (54.345 us; speedup 1.0000x reference)
//
#include <hip/hip_runtime.h>

// ParticleI2cCell: pairwise Gaussian loglik (P x P, D=4) + two row-LSEs.
// smoothed[i] = log(sum_j e_ij*exp(w_j)) - log(sum_j e_ij*exp(lw_j))
// e_ij = exp(m_i . s_j - ||s_j||^2/2)   [exp(-||m_i||^2/2) cancels in the
// log-ratio and is dropped].
//
// R4 lesson: the partials-over-j structure (rows on lanes) forces a 16.8MB
// round-trip + a latency-bound reduce kernel. This version inverts the
// mapping: lanes = j, rows register-tiled per block (TR=16), block-internal
// reduction -> no partials, no reduce kernel, 512 blocks.

constexpr float LOG2E = 1.4426950408889634f;
constexpr float LN2   = 0.6931471805599453f;

// ---------------- precompute: j-table [P][8] AoS + means SoA [4][P] --------
__global__ __launch_bounds__(256) void precompute_kernel(
    const float* __restrict__ particles,
    const float* __restrict__ samples,
    const float* __restrict__ weights,
    const float* __restrict__ log_weights,
    const float* __restrict__ A,
    const float* __restrict__ B,
    const float* __restrict__ log_sigma,
    float* __restrict__ jdata,   // [P][8]: {LOG2E*s0..s3, K*||s||^2, e^lw, e^w, 0}
    float* __restrict__ msoa,    // [4][P] scaled means
    int P)
{
    int i = blockIdx.x * blockDim.x + threadIdx.x;
    if (i >= P) return;

    const float K = -0.5f * LOG2E;

    float inv_s[4];
#pragma unroll
    for (int k = 0; k < 4; ++k)
        inv_s[k] = __builtin_amdgcn_exp2f(-log_sigma[k] * LOG2E);

    float4 sv = reinterpret_cast<const float4*>(samples)[i];
    float s0 = sv.x * inv_s[0], s1 = sv.y * inv_s[1];
    float s2 = sv.z * inv_s[2], s3 = sv.w * inv_s[3];
    float sn = s0*s0 + s1*s1 + s2*s2 + s3*s3;

    float4* jd = reinterpret_cast<float4*>(jdata + (size_t)i * 8);
    jd[0] = make_float4(LOG2E*s0, LOG2E*s1, LOG2E*s2, LOG2E*s3);
    jd[1] = make_float4(K * sn,
                        __builtin_amdgcn_exp2f(log_weights[i] * LOG2E),
                        __builtin_amdgcn_exp2f(weights[i] * LOG2E),
                        0.f);

    const float2* p2 = reinterpret_cast<const float2*>(particles) + (size_t)i * 3;
    float2 x01 = p2[0], x23 = p2[1], u01 = p2[2];
    float x[4] = {x01.x, x01.y, x23.x, x23.y};
    float u[2] = {u01.x, u01.y};
#pragma unroll
    for (int k = 0; k < 4; ++k) {
        float mean =       A[k*4+0] * x[0];
        mean = fmaf(A[k*4+1], x[1], mean);
        mean = fmaf(A[k*4+2], x[2], mean);
        mean = fmaf(A[k*4+3], x[3], mean);
        mean = fmaf(B[k*2+0], u[0], mean);
        mean = fmaf(B[k*2+1], u[1], mean);
        msoa[(size_t)k * P + i] = mean * inv_s[k];
    }
}

// ---------------- main kernel: TR rows/block, lanes sweep all j ------------
// grid = ceil(P/TR). Double-buffered LDS chunks of JCHUNK j-entries staged
// from L2 (T14 split: loads issued before compute, LDS write after).
template <int TR, int BLOCK, int JCHUNK>
__global__ __launch_bounds__(BLOCK) void pair_all(
    const float* __restrict__ jdata,   // [P][8]
    const float* __restrict__ msoa,    // [4][P]
    float* __restrict__ out, int P)
{
    constexpr int F4C = JCHUNK * 2;          // float4s per chunk
    constexpr int F4T = F4C / BLOCK;         // float4s staged per thread (4)
    constexpr int ITC = JCHUNK / BLOCK;      // j-iters per thread per chunk (2)

    __shared__ float4 lds[2][F4C];

    const int tid = threadIdx.x;
    const int rowBase = blockIdx.x * TR;

    // uniform row means for this block's TR rows
    float m0[TR], m1[TR], m2[TR], m3[TR];
#pragma unroll
    for (int r = 0; r < TR; ++r) {
        int row = rowBase + r;
        bool ok = row < P;
        m0[r] = ok ? msoa[0 * (size_t)P + row] : 0.f;
        m1[r] = ok ? msoa[1 * (size_t)P + row] : 0.f;
        m2[r] = ok ? msoa[2 * (size_t)P + row] : 0.f;
        m3[r] = ok ? msoa[3 * (size_t)P + row] : 0.f;
    }

    const float4* jf = reinterpret_cast<const float4*>(jdata);
    const int totalF4 = P * 2;
    const int NC = (totalF4 + F4C - 1) / F4C;

    // stage chunk 0
    float4 stage[F4T];
    const float4 zero4 = make_float4(0.f, 0.f, 0.f, 0.f);
#pragma unroll
    for (int q = 0; q < F4T; ++q) {
        int f = tid + q * BLOCK;
        stage[q] = (f < totalF4) ? jf[f] : zero4;
    }
#pragma unroll
    for (int q = 0; q < F4T; ++q)
        lds[0][tid + q * BLOCK] = stage[q];
    __syncthreads();

    float a1[TR], a2[TR];
#pragma unroll
    for (int r = 0; r < TR; ++r) { a1[r] = 0.f; a2[r] = 0.f; }

    for (int c = 0; c < NC; ++c) {
        const int cur = c & 1;
        // issue next chunk's global loads (hidden under compute)
        if (c + 1 < NC) {
#pragma unroll
            for (int q = 0; q < F4T; ++q) {
                int f = (c + 1) * F4C + tid + q * BLOCK;
                stage[q] = (f < totalF4) ? jf[f] : zero4;
            }
        }
        // compute this chunk: each thread owns entries tid + it*BLOCK
#pragma unroll
        for (int it = 0; it < ITC; ++it) {
            int e = tid + it * BLOCK;
            float4 av = lds[cur][2 * e];
            float4 bv = lds[cur][2 * e + 1];
#pragma unroll
            for (int r = 0; r < TR; ++r) {
                float t = fmaf(m0[r], av.x, bv.x);
                t = fmaf(m1[r], av.y, t);
                t = fmaf(m2[r], av.z, t);
                t = fmaf(m3[r], av.w, t);
                float e2 = __builtin_amdgcn_exp2f(t);
                a1[r] = fmaf(e2, bv.y, a1[r]);
                a2[r] = fmaf(e2, bv.z, a2[r]);
            }
        }
        if (c + 1 < NC) {
#pragma unroll
            for (int q = 0; q < F4T; ++q)
                lds[cur ^ 1][tid + q * BLOCK] = stage[q];
            __syncthreads();
        }
    }

    // ---- block reduction: butterfly within wave, fixed-order across waves
#pragma unroll
    for (int r = 0; r < TR; ++r) {
#pragma unroll
        for (int mask = 32; mask >= 1; mask >>= 1) {
            a1[r] += __shfl_xor(a1[r], mask, 64);
            a2[r] += __shfl_xor(a2[r], mask, 64);
        }
    }

    __syncthreads();   // done reading LDS chunks; reuse as reduction scratch
    float* red = reinterpret_cast<float*>(lds);
    const int lane = tid & 63;
    const int w = tid >> 6;
    if (lane == 0) {
#pragma unroll
        for (int r = 0; r < TR; ++r) {
            red[w * 2 * TR + r]      = a1[r];
            red[w * 2 * TR + TR + r] = a2[r];
        }
    }
    __syncthreads();
    if (tid < TR) {
        float s1 = 0.f, s2 = 0.f;
#pragma unroll
        for (int ww = 0; ww < BLOCK / 64; ++ww) {
            s1 += red[ww * 2 * TR + tid];
            s2 += red[ww * 2 * TR + TR + tid];
        }
        int row = rowBase + tid;
        if (row < P)
            out[row] = (__builtin_amdgcn_logf(s2) - __builtin_amdgcn_logf(s1)) * LN2;
    }
}

extern "C" void kernel_launch(void* const* d_in, const int* in_sizes, int n_in,
                              void* d_out, int out_size, void* d_ws, size_t ws_size,
                              hipStream_t stream)
{
    const float* particles   = (const float*)d_in[0];
    const float* samples     = (const float*)d_in[1];
    const float* weights     = (const float*)d_in[2];
    const float* log_weights = (const float*)d_in[3];
    const float* A           = (const float*)d_in[4];
    const float* B           = (const float*)d_in[5];
    const float* log_sigma   = (const float*)d_in[6];

    const int P = in_sizes[2];  // weights is (P,)

    // ws layout: jdata P*8 | msoa 4*P   (393 KB at P=8192)
    float* jdata = (float*)d_ws;
    float* msoa  = jdata + (size_t)P * 8;

    precompute_kernel<<<(P + 255) / 256, 256, 0, stream>>>(
        particles, samples, weights, log_weights, A, B, log_sigma,
        jdata, msoa, P);

    constexpr int TR = 16, BLOCK = 256, JCHUNK = 512;
    int grid = (P + TR - 1) / TR;            // 512 blocks at P=8192
    pair_all<TR, BLOCK, JCHUNK><<<grid, BLOCK, 0, stream>>>(
        jdata, msoa, (float*)d_out, P);
}

// Round 6
// 39.048 us; speedup vs baseline: 1.3917x; 1.3917x over previous
//
#include <hip/hip_runtime.h>

// ParticleI2cCell: pairwise Gaussian loglik (P x P, D=4) + two row-LSEs.
// smoothed[i] = log(sum_j e_ij*exp(w_j)) - log(sum_j e_ij*exp(lw_j))
// e_ij = exp(m_i . s_j - ||s_j||^2/2)   [exp(-||m_i||^2/2) cancels in the
// log-ratio and is dropped].
//
// R5 lesson: every structure so far was latency-bound (VALUBusy 23-29%,
// occupancy <=19%). This version targets FULL occupancy: R=1 row/thread,
// NJ=64 j-slices -> 2048 blocks x 256 thr = 524288 threads = 32 waves/CU.
// Hot kernel: no LDS, no __syncthreads, no cross-lane ops; j-entries are
// wave-uniform s_load's from the L2-resident 256KB table. Partials [64][P]
// (4MB) reduced by one 64-lane group per row (lane = slice).

constexpr float LOG2E = 1.4426950408889634f;
constexpr float LN2   = 0.6931471805599453f;

// ---------------- precompute: j-table [P][8] AoS + means SoA [4][P] --------
__global__ __launch_bounds__(256) void precompute_k(
    const float* __restrict__ particles,
    const float* __restrict__ samples,
    const float* __restrict__ weights,
    const float* __restrict__ log_weights,
    const float* __restrict__ A,
    const float* __restrict__ B,
    const float* __restrict__ log_sigma,
    float* __restrict__ jdata,   // [P][8]: {LOG2E*s0..s3, K*||s||^2, e^lw, e^w, 0}
    float* __restrict__ msoa,    // [4][P] scaled means
    int P)
{
    int i = blockIdx.x * blockDim.x + threadIdx.x;
    if (i >= P) return;

    const float K = -0.5f * LOG2E;

    float inv_s[4];
#pragma unroll
    for (int k = 0; k < 4; ++k)
        inv_s[k] = __builtin_amdgcn_exp2f(-log_sigma[k] * LOG2E);

    float4 sv = reinterpret_cast<const float4*>(samples)[i];
    float s0 = sv.x * inv_s[0], s1 = sv.y * inv_s[1];
    float s2 = sv.z * inv_s[2], s3 = sv.w * inv_s[3];
    float sn = s0*s0 + s1*s1 + s2*s2 + s3*s3;

    float4* jd = reinterpret_cast<float4*>(jdata + (size_t)i * 8);
    jd[0] = make_float4(LOG2E*s0, LOG2E*s1, LOG2E*s2, LOG2E*s3);
    jd[1] = make_float4(K * sn,
                        __builtin_amdgcn_exp2f(log_weights[i] * LOG2E),
                        __builtin_amdgcn_exp2f(weights[i] * LOG2E),
                        0.f);

    const float2* p2 = reinterpret_cast<const float2*>(particles) + (size_t)i * 3;
    float2 x01 = p2[0], x23 = p2[1], u01 = p2[2];
    float x[4] = {x01.x, x01.y, x23.x, x23.y};
    float u[2] = {u01.x, u01.y};
#pragma unroll
    for (int k = 0; k < 4; ++k) {
        float mean =       A[k*4+0] * x[0];
        mean = fmaf(A[k*4+1], x[1], mean);
        mean = fmaf(A[k*4+2], x[2], mean);
        mean = fmaf(A[k*4+3], x[3], mean);
        mean = fmaf(B[k*2+0], u[0], mean);
        mean = fmaf(B[k*2+1], u[1], mean);
        msoa[(size_t)k * P + i] = mean * inv_s[k];
    }
}

// ---------------- pair kernel: 1 row/thread, NJ j-slices, full occupancy ---
// grid = (NJ, P/BLOCK) = (64, 32) = 2048 blocks -> 8 blocks/CU.
template <int BLOCK, int JSLICE>
__global__ __launch_bounds__(BLOCK, 8) void pair_rows(
    const float* __restrict__ jdata,   // [P][8]
    const float* __restrict__ msoa,    // [4][P]
    float* __restrict__ part1,         // [NJ][P]
    float* __restrict__ part2,         // [NJ][P]
    int P)
{
    const int tid = threadIdx.x;
    const int jc  = blockIdx.x;
    const int row = blockIdx.y * BLOCK + tid;

    const float m0 = msoa[0 * (size_t)P + row];
    const float m1 = msoa[1 * (size_t)P + row];
    const float m2 = msoa[2 * (size_t)P + row];
    const float m3 = msoa[3 * (size_t)P + row];

    float a1 = 0.f, a2 = 0.f;

    // wave-uniform slice walk: compiler emits scalar loads from L2
    const float4* jf = reinterpret_cast<const float4*>(jdata) +
                       (size_t)jc * JSLICE * 2;
#pragma unroll 4
    for (int jj = 0; jj < JSLICE; ++jj) {
        float4 av = jf[2 * jj];
        float4 bv = jf[2 * jj + 1];
        float t = fmaf(m0, av.x, bv.x);
        t = fmaf(m1, av.y, t);
        t = fmaf(m2, av.z, t);
        t = fmaf(m3, av.w, t);
        float e = __builtin_amdgcn_exp2f(t);
        a1 = fmaf(e, bv.y, a1);
        a2 = fmaf(e, bv.z, a2);
    }

    part1[(size_t)jc * P + row] = a1;   // coalesced
    part2[(size_t)jc * P + row] = a2;
}

// ---------------- reduce: one 64-lane group per row (lane = slice) ---------
// grid = P/4 blocks of 256. Butterfly is fixed-order -> deterministic.
template <int NJ>
__global__ __launch_bounds__(256) void reduce_k(
    const float* __restrict__ part1,
    const float* __restrict__ part2,
    float* __restrict__ out, int P)
{
    const int lane = threadIdx.x & 63;          // = j-slice
    const int grp  = threadIdx.x >> 6;          // 0..3
    const int row  = blockIdx.x * 4 + grp;

    float s1 = part1[(size_t)lane * P + row];
    float s2 = part2[(size_t)lane * P + row];
#pragma unroll
    for (int mask = 32; mask >= 1; mask >>= 1) {
        s1 += __shfl_xor(s1, mask, 64);
        s2 += __shfl_xor(s2, mask, 64);
    }
    if (lane == 0)
        out[row] = (__builtin_amdgcn_logf(s2) - __builtin_amdgcn_logf(s1)) * LN2;
}

extern "C" void kernel_launch(void* const* d_in, const int* in_sizes, int n_in,
                              void* d_out, int out_size, void* d_ws, size_t ws_size,
                              hipStream_t stream)
{
    const float* particles   = (const float*)d_in[0];
    const float* samples     = (const float*)d_in[1];
    const float* weights     = (const float*)d_in[2];
    const float* log_weights = (const float*)d_in[3];
    const float* A           = (const float*)d_in[4];
    const float* B           = (const float*)d_in[5];
    const float* log_sigma   = (const float*)d_in[6];

    const int P = in_sizes[2];  // weights is (P,)

    constexpr int BLOCK = 256;
    constexpr int NJ = 64;
    const int JSLICE = P / NJ;                  // 128 at P=8192

    // ws layout: jdata P*8 | msoa 4*P | part1 NJ*P | part2 NJ*P  (~4.6MB)
    float* jdata = (float*)d_ws;
    float* msoa  = jdata + (size_t)P * 8;
    float* part1 = msoa + (size_t)P * 4;
    float* part2 = part1 + (size_t)NJ * P;

    precompute_k<<<(P + BLOCK - 1) / BLOCK, BLOCK, 0, stream>>>(
        particles, samples, weights, log_weights, A, B, log_sigma,
        jdata, msoa, P);

    dim3 grid(NJ, P / BLOCK);                   // (64, 32) = 2048 blocks
    if (JSLICE == 128) {
        pair_rows<BLOCK, 128><<<grid, BLOCK, 0, stream>>>(
            jdata, msoa, part1, part2, P);
    } else if (JSLICE == 64) {
        pair_rows<BLOCK, 64><<<grid, BLOCK, 0, stream>>>(
            jdata, msoa, part1, part2, P);
    } else {
        pair_rows<BLOCK, 256><<<grid, BLOCK, 0, stream>>>(
            jdata, msoa, part1, part2, P);
    }

    reduce_k<NJ><<<P / 4, 256, 0, stream>>>(part1, part2, (float*)d_out, P);
}